// Round 18
// baseline (71.128 us; speedup 1.0000x reference)
//
#include <hip/hip_runtime.h>
#include <hip/hip_bf16.h>

#define NHID 64
#define NT   63
#define NBD  512
#define HLDS_STR 72   // shorts per h row (144 B): b128 reads / b64 writes 2-way (free)
#define XSTR 35       // floats per xs row

typedef __attribute__((ext_vector_type(8))) short bf16x8;
typedef __attribute__((ext_vector_type(4))) float f32x4;

__device__ __forceinline__ float tanh_fast(float x) {
    // 1 - 2/(e^{2x}+1): exact for +-large x; tanh_fast(0) == 0 bitwise
    const float e = __expf(2.0f * x);
    const float r = __builtin_amdgcn_rcpf(e + 1.0f);
    return 1.0f - 2.0f * r;
}

__device__ __forceinline__ unsigned int cvt_pk_bf16(float lo, float hi) {
    unsigned int r;
    asm("v_cvt_pk_bf16_f32 %0, %1, %2" : "=v"(r) : "v"(lo), "v"(hi));
    return r;   // lo16 = bf16(lo), hi16 = bf16(hi), RNE
}

// skew-diagonal geometry (weights/k_fc only)
#define SKEW_R0(t)  ((t) > 31 ? (t) - 31 : 0)
#define SKEW_R1(t)  ((t) < 31 ? (t) : 31)
#define SKEW_OFF(t) ((t) < 32 ? ((t) * ((t) + 1)) >> 1 : 1024 - (((63 - (t)) * (64 - (t))) >> 1))

// raw barrier: waits LDS ops only — global stores stay in flight
#define LGKM_BARRIER() do {                                   \
    asm volatile("s_waitcnt lgkmcnt(0)" ::: "memory");        \
    __builtin_amdgcn_s_barrier();                             \
    asm volatile("" ::: "memory");                            \
} while (0)

// ---------------------------------------------------------------------------
// k_main: blocks 0..255 = RNN, 512 threads = 8 waves = (o-quarter wo 0..3) x
// (r-half wr). Each block owns TWO sequences A=2*blk, B=2*blk+1 (same
// direction -> shared weight fragments). Per wave per step: 8 ds_read_b128 +
// 8 MFMA (4 independent 2-deep chains) + 8 tanh across two independent
// sequence chains — dual-seq in-wave ILP (R13, -42%/seq) AT 2 waves/SIMD
// (R12's occupancy), the one untried combination of the two proven levers.
// Dead-window skip per wr; direct exec-masked global acts store.
// Blocks >= 256 = w_fc pre-swizzle (2016 blocks x 512 thr).
// acts layout: slot = bd*65536 + r*1984 + t*64 + o (bijective on valid cells).
// ---------------------------------------------------------------------------
__global__ __launch_bounds__(512, 2) void k_main(
    const float* __restrict__ x,
    const float* __restrict__ w_in,
    const float* __restrict__ b_in,
    const float* __restrict__ w_state,
    const float* __restrict__ b_state,
    unsigned short* __restrict__ acts_c,
    const float* __restrict__ w_fc,
    unsigned short* __restrict__ wt_swz)
{
    __shared__ __align__(16) unsigned short hA0[33 * HLDS_STR];
    __shared__ __align__(16) unsigned short hA1[33 * HLDS_STR];
    __shared__ __align__(16) unsigned short hB0[33 * HLDS_STR];
    __shared__ __align__(16) unsigned short hB1[33 * HLDS_STR];
    __shared__ float xsA[32 * XSTR];
    __shared__ float xsB[32 * XSTR];

    const int tid = threadIdx.x;

    if (blockIdx.x >= 256) {
        // ---------------- w_fc pre-swizzle path (512-thr blocks) ----------------
        const int rel = blockIdx.x - 256;         // 0..2015
        const int t   = rel >> 5;                 // 63 t-regions x 32 sub
        const int sub = rel & 31;
        const int r0 = SKEW_R0(t), r1 = SKEW_R1(t);
        const int cnt = r1 - r0 + 1;
        const int span = cnt << 10;               // shorts per d
        int f = sub * 4096 + tid * 8;             // short index within t-region
        const int fdst = f;
        if (f >= 4 * span) return;
        int d = 0;
        while (f >= span) { f -= span; ++d; }     // <=3 iters
        const int ks   = f >> 9;
        const int lane = (f >> 3) & 63;
        const int g = lane >> 4, n = lane & 15;
        unsigned int pk[4];
        #pragma unroll
        for (int jj = 0; jj < 4; ++jj) {
            float v[2] = {0.0f, 0.0f};
            #pragma unroll
            for (int h = 0; h < 2; ++h) {
                const int j = jj * 2 + h;
                const int k = ks * 32 + g * 8 + j;
                const int r = r0 + (k >> 6);
                const int o = k & 63;
                const int c = t - r;              // guaranteed in [0,32)
                if (n < 10)
                    v[h] = w_fc[((((size_t)(d * 64 + o)) << 10) + (r << 5) + c) * 10 + n];
            }
            pk[jj] = cvt_pk_bf16(v[0], v[1]);
        }
        uint4 st; st.x = pk[0]; st.y = pk[1]; st.z = pk[2]; st.w = pk[3];
        *(uint4*)(wt_swz + (size_t)SKEW_OFF(t) * 4096 + fdst) = st;
        return;
    }

    // ---------------- RNN path: sequences A and B ----------------
    const int blk = blockIdx.x;
    const int bdA = 2 * blk;
    const int bdB = 2 * blk + 1;
    const int d   = bdA >> 7;                     // same for A and B
    const int bA  = bdA & 127;
    const int lane = tid & 63;
    const int wave = tid >> 6;
    const int wo = wave >> 1;    // o-quarter: o in [wo*16, wo*16+16)
    const int wr = wave & 1;     // r-half:    r in [wr*16, wr*16+16)
    const int n  = lane & 15;
    const int g  = lane >> 4;

    // ---- stage x (both sequences) with direction flips ----
    const bool flr = (d & 1) != 0;
    const bool flc = (d & 2) != 0;
    const float* xbA = x + (size_t)bA * 1024;
    for (int idx = tid; idx < 1024; idx += 512) {
        const int r = idx >> 5, c = idx & 31;
        const int src = (flr ? 31 - r : r) * 32 + (flc ? 31 - c : c);
        xsA[r * XSTR + c] = xbA[src];
        xsB[r * XSTR + c] = xbA[1024 + src];
    }

    // ---- zero all four h buffers ----
    for (int m2 = tid; m2 < (33 * HLDS_STR) / 2; m2 += 512) {
        ((unsigned int*)hA0)[m2] = 0u;
        ((unsigned int*)hA1)[m2] = 0u;
        ((unsigned int*)hB0)[m2] = 0u;
        ((unsigned int*)hB1)[m2] = 0u;
    }

    // ---- A fragments: this wave's o-quarter, 4 K-tiles, single bf16 ----
    // kt: 0 = up ch 0-31, 1 = up 32-63, 2 = same 0-31, 3 = same 32-63
    bf16x8 a[4];
    {
        const int o = wo * 16 + n;
        #pragma unroll
        for (int kt = 0; kt < 4; ++kt) {
            const int s  = kt >> 1;
            const int cb = (kt & 1) * 32 + g * 8;
            bf16x8 w8;
            #pragma unroll
            for (int j = 0; j < 8; ++j) {
                const float w = w_state[((size_t)o * 64 + cb + j) * 2 + s];
                w8[j] = (short)(cvt_pk_bf16(w, 0.0f) & 0xffffu);
            }
            a[kt] = w8;
        }
    }

    float biasr[4], winr[4];
    #pragma unroll
    for (int j = 0; j < 4; ++j) {
        const int o = wo * 16 + g * 4 + j;
        biasr[j] = b_in[o] + b_state[o];
        winr[j]  = w_in[o];
    }

    const int r_out = wr * 16 + n;
    const int rdoff = r_out * HLDS_STR + g * 8;        // B-frag base (h[r-1] row)
    const int wroff = (r_out + 1) * HLDS_STR + wo * 16 + g * 4;  // h write addr
    const int cb0 = wo * 16 + g * 4;
    const int tlo = wr * 16;                           // active window start
    const float* xsA_r = &xsA[r_out * XSTR];
    const float* xsB_r = &xsB[r_out * XSTR];

    unsigned short* actpA = acts_c + (size_t)bdA * 65536 + (size_t)r_out * 1984 + cb0;
    unsigned short* actpB = acts_c + (size_t)bdB * 65536 + (size_t)r_out * 1984 + cb0;

    __syncthreads();

#define MFMA(F, B, C) C = __builtin_amdgcn_mfma_f32_16x16x32_bf16(F, B, C, 0, 0, 0)

#define STEP(T, RA_, WA_, RB_, WB_) do {                                         \
    if ((unsigned)((T) - tlo) < 48u) {                                           \
        const bf16x8 fA0 = *(const bf16x8*)&RA_[rdoff];                          \
        const bf16x8 fA1 = *(const bf16x8*)&RA_[rdoff + 32];                     \
        const bf16x8 fA2 = *(const bf16x8*)&RA_[rdoff + HLDS_STR];               \
        const bf16x8 fA3 = *(const bf16x8*)&RA_[rdoff + HLDS_STR + 32];          \
        const bf16x8 fB0 = *(const bf16x8*)&RB_[rdoff];                          \
        const bf16x8 fB1 = *(const bf16x8*)&RB_[rdoff + 32];                     \
        const bf16x8 fB2 = *(const bf16x8*)&RB_[rdoff + HLDS_STR];               \
        const bf16x8 fB3 = *(const bf16x8*)&RB_[rdoff + HLDS_STR + 32];          \
        f32x4 sAa = {0,0,0,0}, sAb = {0,0,0,0};                                  \
        f32x4 sBa = {0,0,0,0}, sBb = {0,0,0,0};                                  \
        MFMA(a[0], fA0, sAa); MFMA(a[0], fB0, sBa);                              \
        MFMA(a[2], fA2, sAb); MFMA(a[2], fB2, sBb);                              \
        MFMA(a[1], fA1, sAa); MFMA(a[1], fB1, sBa);                              \
        MFMA(a[3], fA3, sAb); MFMA(a[3], fB3, sBb);                              \
        const int c_ = (T) - r_out;                                              \
        const bool stv = (unsigned)c_ < 32u;                                     \
        const float xvA = stv ? xsA_r[c_ & 31] : 0.0f;                           \
        const float xvB = stv ? xsB_r[c_ & 31] : 0.0f;                           \
        {                                                                        \
            const float h0 = tanh_fast(sAa[0] + sAb[0] + biasr[0] + winr[0] * xvA); \
            const float h1 = tanh_fast(sAa[1] + sAb[1] + biasr[1] + winr[1] * xvA); \
            const float h2 = tanh_fast(sAa[2] + sAb[2] + biasr[2] + winr[2] * xvA); \
            const float h3 = tanh_fast(sAa[3] + sAb[3] + biasr[3] + winr[3] * xvA); \
            uint2 pk; pk.x = cvt_pk_bf16(h0, h1); pk.y = cvt_pk_bf16(h2, h3);    \
            *(uint2*)&WA_[wroff] = pk;                                           \
            if (stv) *(uint2*)(actpA) = pk;                                      \
        }                                                                        \
        {                                                                        \
            const float h0 = tanh_fast(sBa[0] + sBb[0] + biasr[0] + winr[0] * xvB); \
            const float h1 = tanh_fast(sBa[1] + sBb[1] + biasr[1] + winr[1] * xvB); \
            const float h2 = tanh_fast(sBa[2] + sBb[2] + biasr[2] + winr[2] * xvB); \
            const float h3 = tanh_fast(sBa[3] + sBb[3] + biasr[3] + winr[3] * xvB); \
            uint2 pk; pk.x = cvt_pk_bf16(h0, h1); pk.y = cvt_pk_bf16(h2, h3);    \
            *(uint2*)&WB_[wroff] = pk;                                           \
            if (stv) *(uint2*)(actpB) = pk;                                      \
        }                                                                        \
    }                                                                            \
    LGKM_BARRIER();                                                              \
    actpA += 64; actpB += 64;                                                    \
} while (0)

    for (int sp = 0; sp < 31; ++sp) {
        const int t = 2 * sp;
        STEP(t,     hA0, hA1, hB0, hB1);
        STEP(t + 1, hA1, hA0, hB1, hB0);
    }
    STEP(62, hA0, hA1, hB0, hB1);
#undef STEP
#undef MFMA
}

// ---------------------------------------------------------------------------
// k_fc: streaming MFMA GEMM over acts (L3-resident; latency-bound). Block =
// (t, d, mh); 4 waves = 4 M-tiles of 16 batches. A pointer walks +1984 shorts
// per k-pair. unroll 4 -> 8 loads in flight for L3 latency hiding.
// ---------------------------------------------------------------------------
__global__ __launch_bounds__(256, 8) void k_fc(
    const unsigned short* __restrict__ acts_c,
    const unsigned short* __restrict__ wt_swz,
    float* __restrict__ partial)
{
    const int tid = threadIdx.x;
    const int blk = blockIdx.x;          // 63*8
    const int t   = blk >> 3;
    const int d   = (blk >> 1) & 3;
    const int mh  = blk & 1;
    const int lane = tid & 63;
    const int wv  = tid >> 6;
    const int g   = lane >> 4;
    const int n   = lane & 15;

    const int r0 = SKEW_R0(t), r1 = SKEW_R1(t);
    const int cnt = r1 - r0 + 1;
    const int off = SKEW_OFF(t);

    const int tb = d * 128 + mh * 64 + wv * 16;
    const unsigned short* Ap = acts_c + (size_t)(tb + n) * 65536
                             + (size_t)r0 * 1984 + (size_t)t * 64 + g * 8;
    const unsigned short* Bp = wt_swz
        + ((size_t)off * 4 + (size_t)d * cnt) * 1024 + lane * 8;

    f32x4 acc = {0.f, 0.f, 0.f, 0.f};
    #pragma unroll 4
    for (int q = 0; q < cnt; ++q) {
        const bf16x8 a0  = *(const bf16x8*)(Ap);
        const bf16x8 bb0 = *(const bf16x8*)(Bp);
        const bf16x8 a1  = *(const bf16x8*)(Ap + 32);
        const bf16x8 bb1 = *(const bf16x8*)(Bp + 512);
        acc = __builtin_amdgcn_mfma_f32_16x16x32_bf16(a0, bb0, acc, 0, 0, 0);
        acc = __builtin_amdgcn_mfma_f32_16x16x32_bf16(a1, bb1, acc, 0, 0, 0);
        Ap += 1984;
        Bp += 1024;
    }
    const int batch = tb + g * 4;
    #pragma unroll
    for (int reg = 0; reg < 4; ++reg)
        partial[((size_t)t * 512 + batch + reg) * 16 + n] = acc[reg];
}

// ---------------------------------------------------------------------------
// k_out: logits[n] = b_fc[n] + sum_{t,d} partial; log_softmax.
// ---------------------------------------------------------------------------
__global__ __launch_bounds__(256) void k_out(
    const float* __restrict__ partial,
    const float* __restrict__ b_fc,
    float* __restrict__ out)
{
    __shared__ float lred[252 * 10];
    __shared__ float lgs[10];
    __shared__ float lse;
    const int b = blockIdx.x;
    const int tid = threadIdx.x;
    if (tid < 252) {
        const int t = tid >> 2, d = tid & 3;
        const float* p = partial + ((size_t)t * 512 + d * 128 + b) * 16;
        #pragma unroll
        for (int n2 = 0; n2 < 10; ++n2) lred[tid * 10 + n2] = p[n2];
    }
    __syncthreads();
    if (tid < 10) {
        float s = b_fc[tid];
        for (int i = 0; i < 252; ++i) s += lred[i * 10 + tid];
        lgs[tid] = s;
    }
    __syncthreads();
    if (tid == 0) {
        float m = lgs[0];
        for (int nn = 1; nn < 10; ++nn) m = fmaxf(m, lgs[nn]);
        float ssum = 0.0f;
        for (int nn = 0; nn < 10; ++nn) ssum += __expf(lgs[nn] - m);
        lse = m + __logf(ssum);
    }
    __syncthreads();
    if (tid < 10) out[b * 10 + tid] = lgs[tid] - lse;
}

extern "C" void kernel_launch(void* const* d_in, const int* in_sizes, int n_in,
                              void* d_out, int out_size, void* d_ws, size_t ws_size,
                              hipStream_t stream)
{
    const float* x       = (const float*)d_in[0];
    const float* w_in    = (const float*)d_in[1];
    const float* b_in    = (const float*)d_in[2];
    const float* w_state = (const float*)d_in[3];
    const float* b_state = (const float*)d_in[4];
    const float* w_fc    = (const float*)d_in[5];
    const float* b_fc    = (const float*)d_in[6];
    float* out = (float*)d_out;

    // ws layout: wt_swz 8 MiB | partial 2 MiB @8MiB | acts_c 64 MiB @16MiB
    unsigned short* wt_swz = (unsigned short*)d_ws;
    float* partial = (float*)((char*)d_ws + (size_t)(8u << 20));
    unsigned short* acts_c = (unsigned short*)((char*)d_ws + (size_t)(16u << 20));

    // blocks 0-255: RNN (dual-seq, 8 waves); blocks 256-2271: w_fc pre-swizzle
    k_main<<<2272, 512, 0, stream>>>(x, w_in, b_in, w_state, b_state,
                                     acts_c, w_fc, wt_swz);
    k_fc  <<<504, 256, 0, stream>>>(acts_c, wt_swz, partial);
    k_out <<<128, 256, 0, stream>>>(partial, b_fc, out);
}

// Round 19
// 61.676 us; speedup vs baseline: 1.1533x; 1.1533x over previous
//
#include <hip/hip_runtime.h>
#include <hip/hip_bf16.h>

#define NHID 64
#define NT   63
#define NBD  512
#define HLDS_STR 72   // shorts per h row (144 B): b128 reads / b64 writes 2-way (free)
#define XSTR 35       // floats per xs row

typedef __attribute__((ext_vector_type(8))) short bf16x8;
typedef __attribute__((ext_vector_type(4))) float f32x4;

__device__ __forceinline__ float tanh_fast(float x) {
    // 1 - 2/(e^{2x}+1): exact for +-large x; tanh_fast(0) == 0 bitwise
    const float e = __expf(2.0f * x);
    const float r = __builtin_amdgcn_rcpf(e + 1.0f);
    return 1.0f - 2.0f * r;
}

__device__ __forceinline__ unsigned int cvt_pk_bf16(float lo, float hi) {
    unsigned int r;
    asm("v_cvt_pk_bf16_f32 %0, %1, %2" : "=v"(r) : "v"(lo), "v"(hi));
    return r;   // lo16 = bf16(lo), hi16 = bf16(hi), RNE
}

// skew-diagonal geometry (weights/k_fc only)
#define SKEW_R0(t)  ((t) > 31 ? (t) - 31 : 0)
#define SKEW_R1(t)  ((t) < 31 ? (t) : 31)
#define SKEW_OFF(t) ((t) < 32 ? ((t) * ((t) + 1)) >> 1 : 1024 - (((63 - (t)) * (64 - (t))) >> 1))

// raw barrier: waits LDS ops only — global stores stay in flight
#define LGKM_BARRIER() do {                                   \
    asm volatile("s_waitcnt lgkmcnt(0)" ::: "memory");        \
    __builtin_amdgcn_s_barrier();                             \
    asm volatile("" ::: "memory");                            \
} while (0)

// ---------------------------------------------------------------------------
// k_main: blocks 0..511 = RNN (1 block = 1 (dir,batch); 4 waves = o-half wp x
// r-half nt). Single-bf16 weights, 2-deep MFMA chains, direct exec-masked
// global store of acts from compute registers. Blocks >= 512 = w_fc
// pre-swizzle running concurrently. PROVEN BEST (R12/R17: 61.7 us total).
// RECURRENCE PLATEAU (R6-R18, 12 variants): per-CU cost pinned at ~1850
// cyc/step — serial chain (ds_read -> MFMA -> tanh -> ds_write -> barrier)
// x 63 sequential diagonal steps, with only 2 seqs/CU available to overlap.
// acts layout: slot = bd*65536 + r*1984 + t*64 + o (bijective on valid cells).
// ---------------------------------------------------------------------------
__global__ __launch_bounds__(256, 4) void k_main(
    const float* __restrict__ x,
    const float* __restrict__ w_in,
    const float* __restrict__ b_in,
    const float* __restrict__ w_state,
    const float* __restrict__ b_state,
    unsigned short* __restrict__ acts_c,
    const float* __restrict__ w_fc,
    unsigned short* __restrict__ wt_swz)
{
    __shared__ __align__(16) unsigned short h0buf[33 * HLDS_STR];
    __shared__ __align__(16) unsigned short h1buf[33 * HLDS_STR];
    __shared__ float xs[32 * XSTR];

    const int tid = threadIdx.x;

    if (blockIdx.x >= 512) {
        // ---------------- w_fc pre-swizzle path ----------------
        const int rel = blockIdx.x - 512;         // 0..4031
        const int t   = rel >> 6;                 // 63 t-regions x 64 sub
        const int sub = rel & 63;
        const int r0 = SKEW_R0(t), r1 = SKEW_R1(t);
        const int cnt = r1 - r0 + 1;
        const int span = cnt << 10;               // shorts per d
        int f = sub * 2048 + tid * 8;             // short index within t-region
        const int fdst = f;
        if (f >= 4 * span) return;
        int d = 0;
        while (f >= span) { f -= span; ++d; }     // <=3 iters
        const int ks   = f >> 9;
        const int lane = (f >> 3) & 63;
        const int g = lane >> 4, n = lane & 15;
        unsigned int pk[4];
        #pragma unroll
        for (int jj = 0; jj < 4; ++jj) {
            float v[2] = {0.0f, 0.0f};
            #pragma unroll
            for (int h = 0; h < 2; ++h) {
                const int j = jj * 2 + h;
                const int k = ks * 32 + g * 8 + j;
                const int r = r0 + (k >> 6);
                const int o = k & 63;
                const int c = t - r;              // guaranteed in [0,32)
                if (n < 10)
                    v[h] = w_fc[((((size_t)(d * 64 + o)) << 10) + (r << 5) + c) * 10 + n];
            }
            pk[jj] = cvt_pk_bf16(v[0], v[1]);
        }
        uint4 st; st.x = pk[0]; st.y = pk[1]; st.z = pk[2]; st.w = pk[3];
        *(uint4*)(wt_swz + (size_t)SKEW_OFF(t) * 4096 + fdst) = st;
        return;
    }

    // ---------------- RNN path ----------------
    const int bd  = blockIdx.x;
    const int d   = bd >> 7;
    const int b   = bd & 127;
    const int lane = tid & 63;
    const int wave = tid >> 6;
    const int wp = wave & 1;     // o-half: o in [wp*32, wp*32+32)
    const int nt = wave >> 1;    // r-half: r in [nt*16, nt*16+16)
    const int n  = lane & 15;
    const int g  = lane >> 4;

    // ---- stage x with direction flips ----
    const bool flr = (d & 1) != 0;
    const bool flc = (d & 2) != 0;
    const float* xb = x + (size_t)b * 1024;
    for (int idx = tid; idx < 1024; idx += 256) {
        const int r = idx >> 5, c = idx & 31;
        xs[r * XSTR + c] = xb[(flr ? 31 - r : r) * 32 + (flc ? 31 - c : c)];
    }

    // ---- zero both h buffers ----
    for (int m2 = tid; m2 < (33 * HLDS_STR) / 2; m2 += 256) {
        ((unsigned int*)h0buf)[m2] = 0u;
        ((unsigned int*)h1buf)[m2] = 0u;
    }

    // ---- A fragments (weights), single bf16, loaded once ----
    // kt: 0 = up ch 0-31, 1 = up 32-63, 2 = same 0-31, 3 = same 32-63
    bf16x8 a0[4], a1[4];
    #pragma unroll
    for (int wl = 0; wl < 2; ++wl) {
        const int o = wp * 32 + wl * 16 + n;
        #pragma unroll
        for (int kt = 0; kt < 4; ++kt) {
            const int s  = kt >> 1;
            const int cb = (kt & 1) * 32 + g * 8;
            bf16x8 w8;
            #pragma unroll
            for (int j = 0; j < 8; ++j) {
                const float w = w_state[((size_t)o * 64 + cb + j) * 2 + s];
                w8[j] = (short)(cvt_pk_bf16(w, 0.0f) & 0xffffu);
            }
            if (wl == 0) a0[kt] = w8; else a1[kt] = w8;
        }
    }

    float biasr[2][4], winr[2][4];
    #pragma unroll
    for (int wl = 0; wl < 2; ++wl)
        #pragma unroll
        for (int j = 0; j < 4; ++j) {
            const int o = wp * 32 + wl * 16 + g * 4 + j;
            biasr[wl][j] = b_in[o] + b_state[o];
            winr[wl][j]  = w_in[o];
        }

    const int r_out = nt * 16 + n;
    const int rdoff = r_out * HLDS_STR + g * 8;        // B-frag base (h[r-1] row)
    const int wroff = (r_out + 1) * HLDS_STR;          // h write row
    const int cb0 = wp * 32 + g * 4;
    const int tlo = nt * 16;                           // active window start
    const float* xs_r = &xs[r_out * XSTR];

    // direct acts store: slot = bd*65536 + r_out*1984 + t*64 + o
    unsigned short* actp = acts_c + (size_t)bd * 65536 + (size_t)r_out * 1984 + cb0;

    __syncthreads();

#define STEP(T, RB, WB) do {                                                    \
    if ((unsigned)((T) - tlo) < 48u) {                                          \
        const bf16x8 b0 = *(const bf16x8*)&RB[rdoff];                           \
        const bf16x8 b1 = *(const bf16x8*)&RB[rdoff + 32];                      \
        const bf16x8 b2 = *(const bf16x8*)&RB[rdoff + HLDS_STR];                \
        const bf16x8 b3 = *(const bf16x8*)&RB[rdoff + HLDS_STR + 32];           \
        f32x4 s0a = {0,0,0,0}, s0b = {0,0,0,0};                                 \
        f32x4 s1a = {0,0,0,0}, s1b = {0,0,0,0};                                 \
        s0a = __builtin_amdgcn_mfma_f32_16x16x32_bf16(a0[0], b0, s0a, 0,0,0);   \
        s1a = __builtin_amdgcn_mfma_f32_16x16x32_bf16(a1[0], b0, s1a, 0,0,0);   \
        s0b = __builtin_amdgcn_mfma_f32_16x16x32_bf16(a0[2], b2, s0b, 0,0,0);   \
        s1b = __builtin_amdgcn_mfma_f32_16x16x32_bf16(a1[2], b2, s1b, 0,0,0);   \
        s0a = __builtin_amdgcn_mfma_f32_16x16x32_bf16(a0[1], b1, s0a, 0,0,0);   \
        s1a = __builtin_amdgcn_mfma_f32_16x16x32_bf16(a1[1], b1, s1a, 0,0,0);   \
        s0b = __builtin_amdgcn_mfma_f32_16x16x32_bf16(a0[3], b3, s0b, 0,0,0);   \
        s1b = __builtin_amdgcn_mfma_f32_16x16x32_bf16(a1[3], b3, s1b, 0,0,0);   \
        const int c_ = (T) - r_out;                                             \
        const float xv = ((unsigned)c_ < 32u) ? xs_r[c_ & 31] : 0.0f;           \
        uint2 pk0, pk1;                                                         \
        {                                                                       \
            const float h0 = tanh_fast(s0a[0] + s0b[0] + biasr[0][0] + winr[0][0] * xv); \
            const float h1 = tanh_fast(s0a[1] + s0b[1] + biasr[0][1] + winr[0][1] * xv); \
            const float h2 = tanh_fast(s0a[2] + s0b[2] + biasr[0][2] + winr[0][2] * xv); \
            const float h3 = tanh_fast(s0a[3] + s0b[3] + biasr[0][3] + winr[0][3] * xv); \
            pk0.x = cvt_pk_bf16(h0, h1); pk0.y = cvt_pk_bf16(h2, h3);           \
            *(uint2*)&WB[wroff + cb0] = pk0;                                    \
        }                                                                       \
        {                                                                       \
            const float h0 = tanh_fast(s1a[0] + s1b[0] + biasr[1][0] + winr[1][0] * xv); \
            const float h1 = tanh_fast(s1a[1] + s1b[1] + biasr[1][1] + winr[1][1] * xv); \
            const float h2 = tanh_fast(s1a[2] + s1b[2] + biasr[1][2] + winr[1][2] * xv); \
            const float h3 = tanh_fast(s1a[3] + s1b[3] + biasr[1][3] + winr[1][3] * xv); \
            pk1.x = cvt_pk_bf16(h0, h1); pk1.y = cvt_pk_bf16(h2, h3);           \
            *(uint2*)&WB[wroff + cb0 + 16] = pk1;                               \
        }                                                                       \
        if ((unsigned)c_ < 32u) {                                               \
            *(uint2*)(actp)      = pk0;                                         \
            *(uint2*)(actp + 16) = pk1;                                         \
        }                                                                       \
    }                                                                           \
    LGKM_BARRIER();                                                             \
    actp += 64;                                                                 \
} while (0)

    for (int sp = 0; sp < 31; ++sp) {
        const int t = 2 * sp;
        STEP(t,     h0buf, h1buf);
        STEP(t + 1, h1buf, h0buf);
    }
    STEP(62, h0buf, h1buf);
#undef STEP
}

// ---------------------------------------------------------------------------
// k_fc: streaming MFMA GEMM over acts (L3-resident; latency-bound). Block =
// (t, d, mh); 4 waves = 4 M-tiles of 16 batches. A pointer walks +1984 shorts
// per k-pair. unroll 4 -> 8 loads in flight for L3 latency hiding.
// ---------------------------------------------------------------------------
__global__ __launch_bounds__(256, 8) void k_fc(
    const unsigned short* __restrict__ acts_c,
    const unsigned short* __restrict__ wt_swz,
    float* __restrict__ partial)
{
    const int tid = threadIdx.x;
    const int blk = blockIdx.x;          // 63*8
    const int t   = blk >> 3;
    const int d   = (blk >> 1) & 3;
    const int mh  = blk & 1;
    const int lane = tid & 63;
    const int wv  = tid >> 6;
    const int g   = lane >> 4;
    const int n   = lane & 15;

    const int r0 = SKEW_R0(t), r1 = SKEW_R1(t);
    const int cnt = r1 - r0 + 1;
    const int off = SKEW_OFF(t);

    const int tb = d * 128 + mh * 64 + wv * 16;
    const unsigned short* Ap = acts_c + (size_t)(tb + n) * 65536
                             + (size_t)r0 * 1984 + (size_t)t * 64 + g * 8;
    const unsigned short* Bp = wt_swz
        + ((size_t)off * 4 + (size_t)d * cnt) * 1024 + lane * 8;

    f32x4 acc = {0.f, 0.f, 0.f, 0.f};
    #pragma unroll 4
    for (int q = 0; q < cnt; ++q) {
        const bf16x8 a0  = *(const bf16x8*)(Ap);
        const bf16x8 bb0 = *(const bf16x8*)(Bp);
        const bf16x8 a1  = *(const bf16x8*)(Ap + 32);
        const bf16x8 bb1 = *(const bf16x8*)(Bp + 512);
        acc = __builtin_amdgcn_mfma_f32_16x16x32_bf16(a0, bb0, acc, 0, 0, 0);
        acc = __builtin_amdgcn_mfma_f32_16x16x32_bf16(a1, bb1, acc, 0, 0, 0);
        Ap += 1984;
        Bp += 1024;
    }
    const int batch = tb + g * 4;
    #pragma unroll
    for (int reg = 0; reg < 4; ++reg)
        partial[((size_t)t * 512 + batch + reg) * 16 + n] = acc[reg];
}

// ---------------------------------------------------------------------------
// k_out: logits[n] = b_fc[n] + sum_{t,d} partial; log_softmax.
// ---------------------------------------------------------------------------
__global__ __launch_bounds__(256) void k_out(
    const float* __restrict__ partial,
    const float* __restrict__ b_fc,
    float* __restrict__ out)
{
    __shared__ float lred[252 * 10];
    __shared__ float lgs[10];
    __shared__ float lse;
    const int b = blockIdx.x;
    const int tid = threadIdx.x;
    if (tid < 252) {
        const int t = tid >> 2, d = tid & 3;
        const float* p = partial + ((size_t)t * 512 + d * 128 + b) * 16;
        #pragma unroll
        for (int n2 = 0; n2 < 10; ++n2) lred[tid * 10 + n2] = p[n2];
    }
    __syncthreads();
    if (tid < 10) {
        float s = b_fc[tid];
        for (int i = 0; i < 252; ++i) s += lred[i * 10 + tid];
        lgs[tid] = s;
    }
    __syncthreads();
    if (tid == 0) {
        float m = lgs[0];
        for (int nn = 1; nn < 10; ++nn) m = fmaxf(m, lgs[nn]);
        float ssum = 0.0f;
        for (int nn = 0; nn < 10; ++nn) ssum += __expf(lgs[nn] - m);
        lse = m + __logf(ssum);
    }
    __syncthreads();
    if (tid < 10) out[b * 10 + tid] = lgs[tid] - lse;
}

extern "C" void kernel_launch(void* const* d_in, const int* in_sizes, int n_in,
                              void* d_out, int out_size, void* d_ws, size_t ws_size,
                              hipStream_t stream)
{
    const float* x       = (const float*)d_in[0];
    const float* w_in    = (const float*)d_in[1];
    const float* b_in    = (const float*)d_in[2];
    const float* w_state = (const float*)d_in[3];
    const float* b_state = (const float*)d_in[4];
    const float* w_fc    = (const float*)d_in[5];
    const float* b_fc    = (const float*)d_in[6];
    float* out = (float*)d_out;

    // ws layout: wt_swz 8 MiB | partial 2 MiB @8MiB | acts_c 64 MiB @16MiB
    unsigned short* wt_swz = (unsigned short*)d_ws;
    float* partial = (float*)((char*)d_ws + (size_t)(8u << 20));
    unsigned short* acts_c = (unsigned short*)((char*)d_ws + (size_t)(16u << 20));

    // blocks 0-511: RNN; blocks 512-4543: w_fc pre-swizzle (concurrent)
    k_main<<<4544, 256, 0, stream>>>(x, w_in, b_in, w_state, b_state,
                                     acts_c, w_fc, wt_swz);
    k_fc  <<<504, 256, 0, stream>>>(acts_c, wt_swz, partial);
    k_out <<<128, 256, 0, stream>>>(partial, b_fc, out);
}